// Round 13
// baseline (189.694 us; speedup 1.0000x reference)
//
#include <hip/hip_runtime.h>
#include <stdint.h>

// Problem constants (static per reference)
#define NG    256    // graphs
#define NPG   128    // nodes per graph
#define PP    8      // perturbations
#define IND   64     // input dim
#define HID   128    // hidden
#define OUTD  10     // classes

typedef short bf16x8 __attribute__((ext_vector_type(8)));
typedef float f32x4  __attribute__((ext_vector_type(4)));

// RNE f32->bf16 (bit trick) — the verified-correct conversion on this path.
static __device__ __forceinline__ unsigned short f2bf(float f) {
    unsigned int u = __float_as_uint(f);
    u += 0x7FFFu + ((u >> 16) & 1u);
    return (unsigned short)(u >> 16);
}

static __device__ __forceinline__ f32x4 mfma16(bf16x8 a, bf16x8 b, f32x4 c) {
    return __builtin_amdgcn_mfma_f32_16x16x32_bf16(a, b, c, 0, 0, 0);
}

// Barrier that drains ONLY LDS (lgkmcnt), not global loads (vmcnt).
// All cross-wave hazards in this kernel are LDS-only (h1/aggL/pool); global
// traffic is read-only. sched_barrier fences pin motion (rule #18).
static __device__ __forceinline__ void lbar() {
    asm volatile("s_waitcnt lgkmcnt(0)" ::: "memory");
    __builtin_amdgcn_sched_barrier(0);
    __builtin_amdgcn_s_barrier();
    __builtin_amdgcn_sched_barrier(0);
}

// Build one bf16x8 A-fragment directly from the f32 weight matrix W[k][out]
// (k-major, HID out-cols). Identical f2bf on identical f32 values as the old
// prep_weights kernel -> bit-identical fragments.
static __device__ __forceinline__ bf16x8 fragW(const float* __restrict__ W,
                                               int outc, int k0) {
    bf16x8 f;
#pragma unroll
    for (int j = 0; j < 8; ++j)
        f[j] = (short)f2bf(W[(size_t)(k0 + j) * HID + outc]);
    return f;
}

// Load one bf16x8 B-fragment of x directly from global: 32 contiguous bytes
// per lane (2x float4), converted with the SAME f2bf as the old LDS-staged
// path -> bit-identical MFMA inputs. Round-13 change: this replaces the
// entire xb0/xb1 LDS staging subsystem (ISSUE/XWRITE/ld[] and the staged-x
// barrier coupling) — the only subsystem never ablated across the seven
// invariant-42us rounds (r7-r12). The 32 KB tile slab is read by all 8
// waves but fits the CU's 32 KB L1: one L2/L3 pull, then L1 hits.
static __device__ __forceinline__ bf16x8 fragX(const float* __restrict__ src) {
    float4 lo = *(const float4*)(src);
    float4 hi = *(const float4*)(src + 4);
    bf16x8 v;
    v[0] = (short)f2bf(lo.x); v[1] = (short)f2bf(lo.y);
    v[2] = (short)f2bf(lo.z); v[3] = (short)f2bf(lo.w);
    v[4] = (short)f2bf(hi.x); v[5] = (short)f2bf(hi.y);
    v[6] = (short)f2bf(hi.z); v[7] = (short)f2bf(hi.w);
    return v;
}

#define LSTR 136   // bf16 LDS row stride for 128-col tiles (272 B): 68 words
                   // == 4 mod 32 -> only 2-way bank aliasing (free)

// ---------------------------------------------------------------------------
// Fused kernel: ONE BLOCK PER GRAPH (256 blocks x 512 threads = 8 waves).
// r12 kernel with the x-staging subsystem deleted: L1's B-operands are loaded
// register-direct from global (fragX). LDS: h1 + aggL + tails = 70464 B.
// Phase B ping-pongs aggL <-> h1 (h1 dead after phase A). All arithmetic,
// f2bf sites, and ordering identical to r12 -> bit-identical output.
// ---------------------------------------------------------------------------
__global__ __launch_bounds__(512) void graph_fused(
    const float* __restrict__ x,
    const float* __restrict__ Wl1, const float* __restrict__ bl1,
    const float* __restrict__ Wl2, const float* __restrict__ bl2,
    const float* __restrict__ Wg1, const float* __restrict__ bg1,
    const float* __restrict__ Wg2, const float* __restrict__ bg2,
    const float* __restrict__ Wb1, const float* __restrict__ bb1,
    const float* __restrict__ Wb2, const float* __restrict__ bb2,
    const float* __restrict__ Wd1, const float* __restrict__ bd1,
    const float* __restrict__ Wd2, const float* __restrict__ bd2,
    float* __restrict__ out)
{
    // LDS map (bytes):
    //   [0)      h1   128*LSTR shorts (34816)  } phase-B ping-pong
    //   [34816)  aggL 128*LSTR shorts (34816)  }
    //   [69632)  pool 128 f32 (512)
    //   [70144)  z    64 f32  (256)
    //   [70400)  zz   16 f32  (64)
    __shared__ __align__(16) unsigned char smem[70464];
    unsigned short* h1   = (unsigned short*)(smem);
    unsigned short* aggL = (unsigned short*)(smem + 34816);
    float* pool = (float*)(smem + 69632);
    float* z    = (float*)(smem + 70144);
    float* zz   = (float*)(smem + 70400);

    const int g    = blockIdx.x;
    const int tid  = threadIdx.x;
    const int wave = tid >> 6;     // 0..7
    const int lane = tid & 63;
    const int q    = lane >> 4;
    const int r    = lane & 15;
    const int ot   = wave;         // each wave owns output cols [16*ot, 16*ot+16)

    const float* xg = x + (size_t)g * (NPG * PP) * IND;

    // ---- weight fragments, converted in-register ----
    bf16x8 w1f[2];
#pragma unroll
    for (int ks = 0; ks < 2; ++ks)
        w1f[ks] = fragW(Wl1, ot * 16 + r, ks * 32 + q * 8);

    bf16x8 w2f[4];
#pragma unroll
    for (int ks = 0; ks < 4; ++ks)
        w2f[ks] = fragW(Wl2, ot * 16 + r, ks * 32 + q * 8);

    const float4 b1s = *(const float4*)(bl1 + ot * 16 + q * 4);
    const float4 b2s = *(const float4*)(bl2 + ot * 16 + q * 4);

    // per-lane x base: row (nt*16 + r), dims q*8; p adds p*128 rows, ks adds 32
    const float* xlane = xg + (size_t)r * IND + q * 8;

    // ======================= phase A: 8 node-tiles =========================
    for (int nt = 0; nt < 8; ++nt) {
        const float* xt = xlane + (size_t)nt * 16 * IND;

        // layer 1 (K=64) for all 8 perturbations; B-operands register-direct
#pragma unroll
        for (int p = 0; p < PP; ++p) {
            const float* xp = xt + (size_t)p * 128 * IND;
            f32x4 a0 = (f32x4){0.f, 0.f, 0.f, 0.f};
#pragma unroll
            for (int ks = 0; ks < 2; ++ks) {
                bf16x8 xf = fragX(xp + ks * 32);
                a0 = mfma16(w1f[ks], xf, a0);
            }
            ushort4 v0;
            v0.x = f2bf(fmaxf(a0[0] + b1s.x, 0.f));
            v0.y = f2bf(fmaxf(a0[1] + b1s.y, 0.f));
            v0.z = f2bf(fmaxf(a0[2] + b1s.z, 0.f));
            v0.w = f2bf(fmaxf(a0[3] + b1s.w, 0.f));
            *(ushort4*)(&h1[(p * 16 + r) * LSTR + ot * 16 + q * 4]) = v0;
        }
        lbar();   // h1 complete (all 128 cols from all 8 waves)

        // layer 2 (K=128), relu-accumulate over perturbations
        f32x4 agg0 = (f32x4){0.f, 0.f, 0.f, 0.f};
#pragma unroll
        for (int p = 0; p < PP; ++p) {
            f32x4 c0 = (f32x4){0.f, 0.f, 0.f, 0.f};
#pragma unroll
            for (int ks = 0; ks < 4; ++ks) {
                bf16x8 hf = *(const bf16x8*)(&h1[(p * 16 + r) * LSTR + ks * 32 + q * 8]);
                c0 = mfma16(w2f[ks], hf, c0);
            }
            agg0[0] += fmaxf(c0[0] + b2s.x, 0.f);
            agg0[1] += fmaxf(c0[1] + b2s.y, 0.f);
            agg0[2] += fmaxf(c0[2] + b2s.z, 0.f);
            agg0[3] += fmaxf(c0[3] + b2s.w, 0.f);
        }
        // agg for node rows nt*16..+16: exclusive (r, col) region per lane
        {
            ushort4 av;
            av.x = f2bf(agg0[0]);
            av.y = f2bf(agg0[1]);
            av.z = f2bf(agg0[2]);
            av.w = f2bf(agg0[3]);
            *(ushort4*)(&aggL[(nt * 16 + r) * LSTR + ot * 16 + q * 4]) = av;
        }
        lbar();   // h1 rewritable for next tile
    }

    // ================= phase B: 4x (Linear+ReLU) + pool ====================
    int cur = 0;
#pragma unroll
    for (int l = 0; l < 4; ++l) {
        const float* Wlf = (l == 0) ? Wg1 : (l == 1) ? Wg2 : (l == 2) ? Wb1 : Wb2;
        const float* bl  = (l == 0) ? bg1 : (l == 1) ? bg2 : (l == 2) ? bb1 : bb2;

        bf16x8 wf[4];
#pragma unroll
        for (int ks = 0; ks < 4; ++ks)
            wf[ks] = fragW(Wlf, ot * 16 + r, ks * 32 + q * 8);

        unsigned short* Xb = cur ? h1 : aggL;
        unsigned short* Yb = cur ? aggL : h1;

        f32x4 acc[8];
#pragma unroll
        for (int j = 0; j < 8; ++j)
            acc[j] = (f32x4){0.f, 0.f, 0.f, 0.f};

#pragma unroll
        for (int ks = 0; ks < 4; ++ks) {
#pragma unroll
            for (int j = 0; j < 8; ++j) {
                bf16x8 xf = *(const bf16x8*)(&Xb[(j * 16 + r) * LSTR + ks * 32 + q * 8]);
                acc[j] = mfma16(wf[ks], xf, acc[j]);
            }
        }

        if (l < 3) {
            float4 bs = *(const float4*)(bl + ot * 16 + q * 4);
#pragma unroll
            for (int j = 0; j < 8; ++j) {
                ushort4 v;
                v.x = f2bf(fmaxf(acc[j][0] + bs.x, 0.f));
                v.y = f2bf(fmaxf(acc[j][1] + bs.y, 0.f));
                v.z = f2bf(fmaxf(acc[j][2] + bs.z, 0.f));
                v.w = f2bf(fmaxf(acc[j][3] + bs.w, 0.f));
                *(ushort4*)(&Yb[(j * 16 + r) * LSTR + ot * 16 + q * 4]) = v;
            }
            lbar();
            cur ^= 1;
        } else {
            float4 bs = *(const float4*)(bl + ot * 16 + q * 4);
            float s0 = 0.f, s1 = 0.f, s2 = 0.f, s3 = 0.f;
#pragma unroll
            for (int j = 0; j < 8; ++j) {
                s0 += fmaxf(acc[j][0] + bs.x, 0.f);
                s1 += fmaxf(acc[j][1] + bs.y, 0.f);
                s2 += fmaxf(acc[j][2] + bs.z, 0.f);
                s3 += fmaxf(acc[j][3] + bs.w, 0.f);
            }
#pragma unroll
            for (int m = 1; m < 16; m <<= 1) {
                s0 += __shfl_xor(s0, m, 64);
                s1 += __shfl_xor(s1, m, 64);
                s2 += __shfl_xor(s2, m, 64);
                s3 += __shfl_xor(s3, m, 64);
            }
            if (r == 0) {
                pool[ot * 16 + q * 4 + 0] = s0;   // exclusive cols per wave
                pool[ot * 16 + q * 4 + 1] = s1;
                pool[ot * 16 + q * 4 + 2] = s2;
                pool[ot * 16 + q * 4 + 3] = s3;
            }
        }
    }
    lbar();

    // ===================== decoder + log_softmax ===========================
    if (tid < 64) {
        float a0 = bd1[tid], a1 = 0.f, a2 = 0.f, a3 = 0.f;
#pragma unroll
        for (int k = 0; k < 128; k += 4) {
            a0 += pool[k]     * Wd1[(k)     * 64 + tid];
            a1 += pool[k + 1] * Wd1[(k + 1) * 64 + tid];
            a2 += pool[k + 2] * Wd1[(k + 2) * 64 + tid];
            a3 += pool[k + 3] * Wd1[(k + 3) * 64 + tid];
        }
        z[tid] = fmaxf((a0 + a1) + (a2 + a3), 0.f);
    }
    lbar();
    if (tid < OUTD) {
        float b0 = bd2[tid], b1 = 0.f;
#pragma unroll
        for (int k = 0; k < 64; k += 2) {
            b0 += z[k]     * Wd2[(k)     * OUTD + tid];
            b1 += z[k + 1] * Wd2[(k + 1) * OUTD + tid];
        }
        zz[tid] = b0 + b1;
    }
    lbar();
    if (tid == 0) {
        float m = -1e30f;
#pragma unroll
        for (int j = 0; j < OUTD; ++j) m = fmaxf(m, zz[j]);
        float ssum = 0.f;
#pragma unroll
        for (int j = 0; j < OUTD; ++j) ssum += expf(zz[j] - m);
        float ls = logf(ssum);
#pragma unroll
        for (int j = 0; j < OUTD; ++j) out[g * OUTD + j] = zz[j] - m - ls;
    }
}

extern "C" void kernel_launch(void* const* d_in, const int* in_sizes, int n_in,
                              void* d_out, int out_size, void* d_ws, size_t ws_size,
                              hipStream_t stream) {
    const float* x   = (const float*)d_in[0];
    // d_in[1] = ptr (unused; structure is static)
    const float* Wl1 = (const float*)d_in[2];
    const float* bl1 = (const float*)d_in[3];
    const float* Wl2 = (const float*)d_in[4];
    const float* bl2 = (const float*)d_in[5];
    const float* Wg1 = (const float*)d_in[6];
    const float* bg1 = (const float*)d_in[7];
    const float* Wg2 = (const float*)d_in[8];
    const float* bg2 = (const float*)d_in[9];
    const float* Wb1 = (const float*)d_in[10];
    const float* bb1 = (const float*)d_in[11];
    const float* Wb2 = (const float*)d_in[12];
    const float* bb2 = (const float*)d_in[13];
    const float* Wd1 = (const float*)d_in[14];
    const float* bd1 = (const float*)d_in[15];
    const float* Wd2 = (const float*)d_in[16];
    const float* bd2 = (const float*)d_in[17];

    // Single launch: weights converted in-kernel; workspace unused.
    graph_fused<<<NG, 512, 0, stream>>>(x,
                                        Wl1, bl1, Wl2, bl2,
                                        Wg1, bg1, Wg2, bg2,
                                        Wb1, bb1, Wb2, bb2,
                                        Wd1, bd1, Wd2, bd2, (float*)d_out);
}

// Round 14
// 150.441 us; speedup vs baseline: 1.2609x; 1.2609x over previous
//
#include <hip/hip_runtime.h>
#include <stdint.h>

// Problem constants (static per reference)
#define NG    256    // graphs
#define NPG   128    // nodes per graph
#define PP    8      // perturbations
#define IND   64     // input dim
#define HID   128    // hidden
#define OUTD  10     // classes

typedef short bf16x8 __attribute__((ext_vector_type(8)));
typedef float f32x4  __attribute__((ext_vector_type(4)));

// RNE f32->bf16 (bit trick) — the verified-correct conversion on this path.
static __device__ __forceinline__ unsigned short f2bf(float f) {
    unsigned int u = __float_as_uint(f);
    u += 0x7FFFu + ((u >> 16) & 1u);
    return (unsigned short)(u >> 16);
}

static __device__ __forceinline__ f32x4 mfma16(bf16x8 a, bf16x8 b, f32x4 c) {
    return __builtin_amdgcn_mfma_f32_16x16x32_bf16(a, b, c, 0, 0, 0);
}

// Barrier that drains ONLY LDS (lgkmcnt), not global loads (vmcnt) — proven
// safe+fastest in r12. All cross-wave hazards are LDS-only; global traffic is
// read-only x whose consumption is ordered by register-dep vmcnt at XWRITE.
static __device__ __forceinline__ void lbar() {
    asm volatile("s_waitcnt lgkmcnt(0)" ::: "memory");
    __builtin_amdgcn_sched_barrier(0);
    __builtin_amdgcn_s_barrier();
    __builtin_amdgcn_sched_barrier(0);
}

// Build one bf16x8 A-fragment directly from the f32 weight matrix W[k][out]
// (k-major, HID out-cols). Identical f2bf on identical f32 values as the old
// prep kernel -> bit-identical fragments (r11-proven, off critical path).
static __device__ __forceinline__ bf16x8 fragW(const float* __restrict__ W,
                                               int outc, int k0) {
    bf16x8 f;
#pragma unroll
    for (int j = 0; j < 8; ++j)
        f[j] = (short)f2bf(W[(size_t)(k0 + j) * HID + outc]);
    return f;
}

#define LSTR 136   // bf16 LDS row stride for 128-col tiles (272 B): 68 words
                   // == 4 mod 32 -> only 2-way bank aliasing (free)
#define XBS  72    // x-slab stride (64 cols + pad): 36 words == 4 mod 32, same

// ---------------------------------------------------------------------------
// Kernel 1: HALF-GRAPH fused, r12 schedule. 512 blocks x 512 threads,
// LDS 71680 B -> TWO independent blocks per CU. r13's lesson: keep LDS
// staging (conversion amortized 8x across waves). r10's lesson: keep the
// 2-tile-ahead register prefetch and 2 lbar/tile (r10 lost by dropping them).
// The untested mechanism this round isolates: two co-resident blocks with
// independent lbar schedules cross-fill each other's per-phase latency
// bubbles (r8 showed lockstep waves in ONE block cannot).
// Phase A: 4 node-tiles (nodes 64*hh .. +64), per-tile code verbatim r12;
// agg kept in registers (4x ushort4, static unroll). Phase B: 4 layers on
// the 64-row half, ping-pong aggB(dead xb space) <-> h1; partial pool
// written register-direct to workspace. Decoder kernel sums the two halves.
// ---------------------------------------------------------------------------
__global__ __launch_bounds__(512) void half_fused(
    const float* __restrict__ x,
    const float* __restrict__ Wl1, const float* __restrict__ bl1,
    const float* __restrict__ Wl2, const float* __restrict__ bl2,
    const float* __restrict__ Wg1, const float* __restrict__ bg1,
    const float* __restrict__ Wg2, const float* __restrict__ bg2,
    const float* __restrict__ Wb1, const float* __restrict__ bb1,
    const float* __restrict__ Wb2, const float* __restrict__ bb2,
    float* __restrict__ partial)
{
    // LDS map (bytes):
    //   [0)      xb0 128*XBS shorts (18432) \ phase-A x dbuf; aggB (17408 B)
    //   [18432)  xb1 128*XBS shorts (18432) / aliases [0) in phase B
    //   [36864)  h1  128*LSTR shorts (34816)  (phase B uses rows 0..63)
    __shared__ __align__(16) unsigned char smem[71680];
    unsigned short* xb0  = (unsigned short*)(smem);
    unsigned short* xb1  = (unsigned short*)(smem + 18432);
    unsigned short* h1   = (unsigned short*)(smem + 36864);
    unsigned short* aggB = (unsigned short*)(smem);            // phase-B ping

    const int g    = blockIdx.x >> 1;
    const int hh   = blockIdx.x & 1;    // half: nodes [64*hh, 64*hh+64)
    const int tid  = threadIdx.x;
    const int wave = tid >> 6;     // 0..7
    const int lane = tid & 63;
    const int q    = lane >> 4;
    const int r    = lane & 15;
    const int ot   = wave;         // each wave owns output cols [16*ot, +16)

    const float* xg = x + (size_t)g * (NPG * PP) * IND;

    // ---- per-thread staging geometry: 8192 floats/tile, 16 per thread ----
    int sIt[4], cIt[4], gRow[4];
#pragma unroll
    for (int it = 0; it < 4; ++it) {
        int e = it * 2048 + tid * 4;       // float index in the tile slab
        int s = e >> 6;                    // LDS row (p*16 + rr)
        sIt[it]  = s;
        cIt[it]  = e & 63;
        gRow[it] = (s >> 4) * 128 + hh * 64 + (s & 15);  // global row sans nt*16
    }
    float4 ld[4];

#define ISSUE(t)                                                              \
    do {                                                                      \
        _Pragma("unroll")                                                     \
        for (int it = 0; it < 4; ++it)                                        \
            ld[it] = *(const float4*)(xg + (size_t)(gRow[it] + (t) * 16) * IND + cIt[it]); \
    } while (0)

#define XWRITE(dst)                                                           \
    do {                                                                      \
        _Pragma("unroll")                                                     \
        for (int it = 0; it < 4; ++it) {                                      \
            ushort4 w4;                                                       \
            w4.x = f2bf(ld[it].x); w4.y = f2bf(ld[it].y);                     \
            w4.z = f2bf(ld[it].z); w4.w = f2bf(ld[it].w);                     \
            *(ushort4*)(&(dst)[sIt[it] * XBS + cIt[it]]) = w4;                \
        }                                                                     \
    } while (0)

    // ---- weight fragments, converted in-register (overlap tile-0 staging) --
    bf16x8 w1f[2];
#pragma unroll
    for (int ks = 0; ks < 2; ++ks)
        w1f[ks] = fragW(Wl1, ot * 16 + r, ks * 32 + q * 8);

    bf16x8 w2f[4];
#pragma unroll
    for (int ks = 0; ks < 4; ++ks)
        w2f[ks] = fragW(Wl2, ot * 16 + r, ks * 32 + q * 8);

    const float4 b1s = *(const float4*)(bl1 + ot * 16 + q * 4);
    const float4 b2s = *(const float4*)(bl2 + ot * 16 + q * 4);

    // ---- prologue: tile 0 staged, tile 1 in flight ----
    ISSUE(0);
    XWRITE(xb0);   // compiler inserts vmcnt wait via register dep
    ISSUE(1);
    lbar();

    // ======================= phase A: 4 node-tiles =========================
    ushort4 aggv[4];   // bf16-packed agg slice per tile (static-indexed)

#pragma unroll
    for (int nt = 0; nt < 4; ++nt) {
        unsigned short* xcur = (nt & 1) ? xb1 : xb0;

        // layer 1 (K=64) for all 8 perturbations of this tile
#pragma unroll
        for (int p = 0; p < PP; ++p) {
            f32x4 a0 = (f32x4){0.f, 0.f, 0.f, 0.f};
#pragma unroll
            for (int ks = 0; ks < 2; ++ks) {
                bf16x8 xf = *(const bf16x8*)(&xcur[(p * 16 + r) * XBS + ks * 32 + q * 8]);
                a0 = mfma16(w1f[ks], xf, a0);
            }
            ushort4 v0;
            v0.x = f2bf(fmaxf(a0[0] + b1s.x, 0.f));
            v0.y = f2bf(fmaxf(a0[1] + b1s.y, 0.f));
            v0.z = f2bf(fmaxf(a0[2] + b1s.z, 0.f));
            v0.w = f2bf(fmaxf(a0[3] + b1s.w, 0.f));
            *(ushort4*)(&h1[(p * 16 + r) * LSTR + ot * 16 + q * 4]) = v0;
        }
        lbar();   // h1 complete; x loads stay in flight

        // layer 2 (K=128), relu-accumulate over perturbations -> regs
        f32x4 agg0 = (f32x4){0.f, 0.f, 0.f, 0.f};
#pragma unroll
        for (int p = 0; p < PP; ++p) {
            f32x4 c0 = (f32x4){0.f, 0.f, 0.f, 0.f};
#pragma unroll
            for (int ks = 0; ks < 4; ++ks) {
                bf16x8 hf = *(const bf16x8*)(&h1[(p * 16 + r) * LSTR + ks * 32 + q * 8]);
                c0 = mfma16(w2f[ks], hf, c0);
            }
            agg0[0] += fmaxf(c0[0] + b2s.x, 0.f);
            agg0[1] += fmaxf(c0[1] + b2s.y, 0.f);
            agg0[2] += fmaxf(c0[2] + b2s.z, 0.f);
            agg0[3] += fmaxf(c0[3] + b2s.w, 0.f);
        }
        aggv[nt].x = f2bf(agg0[0]);
        aggv[nt].y = f2bf(agg0[1]);
        aggv[nt].z = f2bf(agg0[2]);
        aggv[nt].w = f2bf(agg0[3]);

        // stage next tile's x (register-dep vmcnt orders the in-flight loads)
        if (nt < 3) {
            if (nt & 1) XWRITE(xb0); else XWRITE(xb1);
        }
        if (nt < 2) ISSUE(nt + 2);
        lbar();   // h1 reuse + next xb ready; fresh loads NOT drained
    }

    // materialize agg (64 rows) into aggB (xb space, dead after tile 3);
    // lane-exclusive 8B regions; the final tile lbar precedes us.
#pragma unroll
    for (int nt = 0; nt < 4; ++nt)
        *(ushort4*)(&aggB[(nt * 16 + r) * LSTR + ot * 16 + q * 4]) = aggv[nt];
    lbar();

    // ================= phase B: 4x (Linear+ReLU) + pool ====================
    int cur = 0;
#pragma unroll
    for (int l = 0; l < 4; ++l) {
        const float* Wlf = (l == 0) ? Wg1 : (l == 1) ? Wg2 : (l == 2) ? Wb1 : Wb2;
        const float* bl  = (l == 0) ? bg1 : (l == 1) ? bg2 : (l == 2) ? bb1 : bb2;

        bf16x8 wf[4];
#pragma unroll
        for (int ks = 0; ks < 4; ++ks)
            wf[ks] = fragW(Wlf, ot * 16 + r, ks * 32 + q * 8);

        unsigned short* Xb = cur ? h1 : aggB;
        unsigned short* Yb = cur ? aggB : h1;

        f32x4 acc[4];
#pragma unroll
        for (int j = 0; j < 4; ++j)
            acc[j] = (f32x4){0.f, 0.f, 0.f, 0.f};

#pragma unroll
        for (int ks = 0; ks < 4; ++ks) {
#pragma unroll
            for (int j = 0; j < 4; ++j) {
                bf16x8 xf = *(const bf16x8*)(&Xb[(j * 16 + r) * LSTR + ks * 32 + q * 8]);
                acc[j] = mfma16(wf[ks], xf, acc[j]);
            }
        }

        if (l < 3) {
            float4 bs = *(const float4*)(bl + ot * 16 + q * 4);
#pragma unroll
            for (int j = 0; j < 4; ++j) {
                ushort4 v;
                v.x = f2bf(fmaxf(acc[j][0] + bs.x, 0.f));
                v.y = f2bf(fmaxf(acc[j][1] + bs.y, 0.f));
                v.z = f2bf(fmaxf(acc[j][2] + bs.z, 0.f));
                v.w = f2bf(fmaxf(acc[j][3] + bs.w, 0.f));
                *(ushort4*)(&Yb[(j * 16 + r) * LSTR + ot * 16 + q * 4]) = v;
            }
            lbar();
            cur ^= 1;
        } else {
            float4 bs = *(const float4*)(bl + ot * 16 + q * 4);
            float s0 = 0.f, s1 = 0.f, s2 = 0.f, s3 = 0.f;
#pragma unroll
            for (int j = 0; j < 4; ++j) {
                s0 += fmaxf(acc[j][0] + bs.x, 0.f);
                s1 += fmaxf(acc[j][1] + bs.y, 0.f);
                s2 += fmaxf(acc[j][2] + bs.z, 0.f);
                s3 += fmaxf(acc[j][3] + bs.w, 0.f);
            }
#pragma unroll
            for (int m = 1; m < 16; m <<= 1) {
                s0 += __shfl_xor(s0, m, 64);
                s1 += __shfl_xor(s1, m, 64);
                s2 += __shfl_xor(s2, m, 64);
                s3 += __shfl_xor(s3, m, 64);
            }
            if (r == 0) {   // exclusive cols per (wave, q): direct global write
                float* dst = partial + (size_t)blockIdx.x * HID + ot * 16 + q * 4;
                dst[0] = s0; dst[1] = s1; dst[2] = s2; dst[3] = s3;
            }
        }
    }
#undef ISSUE
#undef XWRITE
}

// ---------------------------------------------------------------------------
// Kernel 2: decoder + log_softmax (r10-proven). 256 blocks x 64 threads.
// ---------------------------------------------------------------------------
__global__ void decoder_k(const float* __restrict__ partial,
                          const float* __restrict__ Wd1, const float* __restrict__ bd1,
                          const float* __restrict__ Wd2, const float* __restrict__ bd2,
                          float* __restrict__ out)
{
    __shared__ float pooled[HID];
    __shared__ float z[64];
    __shared__ float zz[OUTD];

    const int g = blockIdx.x;
    const int t = threadIdx.x;

    const float* p0 = partial + (size_t)(2 * g) * HID;
    const float* p1 = p0 + HID;
    pooled[t]      = p0[t]      + p1[t];
    pooled[t + 64] = p0[t + 64] + p1[t + 64];
    __syncthreads();

    float a0 = bd1[t], a1 = 0.f, a2 = 0.f, a3 = 0.f;
#pragma unroll
    for (int k = 0; k < 128; k += 4) {
        a0 += pooled[k]     * Wd1[(k)     * 64 + t];
        a1 += pooled[k + 1] * Wd1[(k + 1) * 64 + t];
        a2 += pooled[k + 2] * Wd1[(k + 2) * 64 + t];
        a3 += pooled[k + 3] * Wd1[(k + 3) * 64 + t];
    }
    z[t] = fmaxf((a0 + a1) + (a2 + a3), 0.f);
    __syncthreads();

    if (t < OUTD) {
        float b0 = bd2[t], b1 = 0.f;
#pragma unroll
        for (int k = 0; k < 64; k += 2) {
            b0 += z[k]     * Wd2[(k)     * OUTD + t];
            b1 += z[k + 1] * Wd2[(k + 1) * OUTD + t];
        }
        zz[t] = b0 + b1;
    }
    __syncthreads();
    if (t == 0) {
        float m = -1e30f;
#pragma unroll
        for (int j = 0; j < OUTD; ++j) m = fmaxf(m, zz[j]);
        float ssum = 0.f;
#pragma unroll
        for (int j = 0; j < OUTD; ++j) ssum += expf(zz[j] - m);
        float ls = logf(ssum);
#pragma unroll
        for (int j = 0; j < OUTD; ++j) out[g * OUTD + j] = zz[j] - m - ls;
    }
}

extern "C" void kernel_launch(void* const* d_in, const int* in_sizes, int n_in,
                              void* d_out, int out_size, void* d_ws, size_t ws_size,
                              hipStream_t stream) {
    const float* x   = (const float*)d_in[0];
    // d_in[1] = ptr (unused; structure is static)
    const float* Wl1 = (const float*)d_in[2];
    const float* bl1 = (const float*)d_in[3];
    const float* Wl2 = (const float*)d_in[4];
    const float* bl2 = (const float*)d_in[5];
    const float* Wg1 = (const float*)d_in[6];
    const float* bg1 = (const float*)d_in[7];
    const float* Wg2 = (const float*)d_in[8];
    const float* bg2 = (const float*)d_in[9];
    const float* Wb1 = (const float*)d_in[10];
    const float* bb1 = (const float*)d_in[11];
    const float* Wb2 = (const float*)d_in[12];
    const float* bb2 = (const float*)d_in[13];
    const float* Wd1 = (const float*)d_in[14];
    const float* bd1 = (const float*)d_in[15];
    const float* Wd2 = (const float*)d_in[16];
    const float* bd2 = (const float*)d_in[17];

    float* partial = (float*)d_ws;   // 512 x 128 f32; fully overwritten before read

    half_fused<<<NG * 2, 512, 0, stream>>>(x,
                                           Wl1, bl1, Wl2, bl2,
                                           Wg1, bg1, Wg2, bg2,
                                           Wb1, bb1, Wb2, bb2, partial);
    decoder_k<<<NG, 64, 0, stream>>>(partial, Wd1, bd1, Wd2, bd2, (float*)d_out);
}

// Round 15
// 143.501 us; speedup vs baseline: 1.3219x; 1.0484x over previous
//
#include <hip/hip_runtime.h>
#include <stdint.h>

// Problem constants (static per reference)
#define NG    256    // graphs
#define NPG   128    // nodes per graph
#define PP    8      // perturbations
#define IND   64     // input dim
#define HID   128    // hidden
#define OUTD  10     // classes

typedef short bf16x8 __attribute__((ext_vector_type(8)));
typedef float f32x4  __attribute__((ext_vector_type(4)));

// RNE f32->bf16 (bit trick) — the verified-correct conversion on this path.
static __device__ __forceinline__ unsigned short f2bf(float f) {
    unsigned int u = __float_as_uint(f);
    u += 0x7FFFu + ((u >> 16) & 1u);
    return (unsigned short)(u >> 16);
}

static __device__ __forceinline__ f32x4 mfma16(bf16x8 a, bf16x8 b, f32x4 c) {
    return __builtin_amdgcn_mfma_f32_16x16x32_bf16(a, b, c, 0, 0, 0);
}

// Barrier that drains ONLY LDS (lgkmcnt), not global loads (vmcnt).
// __syncthreads() emits s_waitcnt vmcnt(0) lgkmcnt(0) before s_barrier, which
// drains the x-prefetch burst every tile. All cross-wave hazards in this
// kernel are LDS-only; the only in-loop global traffic is read-only x, whose
// consumption is ordered by the compiler's automatic register-dependency
// vmcnt at XWRITE. sched_barrier fences pin instruction motion (rule #18).
static __device__ __forceinline__ void lbar() {
    asm volatile("s_waitcnt lgkmcnt(0)" ::: "memory");
    __builtin_amdgcn_sched_barrier(0);
    __builtin_amdgcn_s_barrier();
    __builtin_amdgcn_sched_barrier(0);
}

// Build one bf16x8 A-fragment directly from the f32 weight matrix W[k][out]
// (k-major, HID out-cols): elements k0..k0+7 of column outc. Identical f2bf
// on identical f32 values as the old prep_weights kernel -> bit-identical.
static __device__ __forceinline__ bf16x8 fragW(const float* __restrict__ W,
                                               int outc, int k0) {
    bf16x8 f;
#pragma unroll
    for (int j = 0; j < 8; ++j)
        f[j] = (short)f2bf(W[(size_t)(k0 + j) * HID + outc]);
    return f;
}

#define LSTR 136   // bf16 LDS row stride for 128-col tiles (272 B): 68 words
                   // == 4 mod 32 -> only 2-way bank aliasing (free)
#define XBS  72    // x-slab stride (64 cols + pad): 36 words == 4 mod 32, same

// ---------------------------------------------------------------------------
// Fused kernel: ONE BLOCK PER GRAPH (256 blocks x 512 threads = 8 waves).
// SESSION CHAMPION (round 12, 141.8 us): single launch, in-kernel weight
// conversion, LDS-staged x with 2-tile-ahead register prefetch, lgkmcnt-only
// barriers. 14-round ledger: the ~41.5 us kernel plateau is invariant under
// barrier count (r7), waves/SIMD (r8), LDS traffic (r9), vmcnt drains (r12);
// removing staging (r13: 2x worse) and splitting into independent blocks
// (r10/r14: worse) both regress. Latency-composite, no saturated pipe;
// remaining bench time is dominated by harness poison fills (~83 us/iter).
// ---------------------------------------------------------------------------
__global__ __launch_bounds__(512) void graph_fused(
    const float* __restrict__ x,
    const float* __restrict__ Wl1, const float* __restrict__ bl1,
    const float* __restrict__ Wl2, const float* __restrict__ bl2,
    const float* __restrict__ Wg1, const float* __restrict__ bg1,
    const float* __restrict__ Wg2, const float* __restrict__ bg2,
    const float* __restrict__ Wb1, const float* __restrict__ bb1,
    const float* __restrict__ Wb2, const float* __restrict__ bb2,
    const float* __restrict__ Wd1, const float* __restrict__ bd1,
    const float* __restrict__ Wd2, const float* __restrict__ bd2,
    float* __restrict__ out)
{
    // LDS map (bytes):
    //   [0)      xb0 128*XBS shorts (18432) \  phase A x dbuf; aliased by
    //   [18432)  xb1 128*XBS shorts (18432) /  bufB (34816 B) in phase B
    //   [36864)  h1   128*LSTR shorts (34816)
    //   [71680)  aggL 128*LSTR shorts (34816)
    //   [106496) pool 128 f32 (512)
    //   [107008) z    64 f32  (256)
    //   [107264) zz   16 f32  (64)
    __shared__ __align__(16) unsigned char smem[107328];
    unsigned short* xb0  = (unsigned short*)(smem);
    unsigned short* xb1  = (unsigned short*)(smem + 18432);
    unsigned short* h1   = (unsigned short*)(smem + 36864);
    unsigned short* aggL = (unsigned short*)(smem + 71680);
    unsigned short* bufB = (unsigned short*)(smem);            // phase-B ping
    float* pool = (float*)(smem + 106496);
    float* z    = (float*)(smem + 107008);
    float* zz   = (float*)(smem + 107264);

    const int g    = blockIdx.x;
    const int tid  = threadIdx.x;
    const int wave = tid >> 6;     // 0..7
    const int lane = tid & 63;
    const int q    = lane >> 4;
    const int r    = lane & 15;
    const int ot   = wave;         // each wave owns output cols [16*ot, 16*ot+16)

    const float* xg = x + (size_t)g * (NPG * PP) * IND;

    // ---- per-thread staging geometry: 8192 elems/tile, 16 per thread ----
    int sIt[4], cIt[4], gRow[4];
#pragma unroll
    for (int it = 0; it < 4; ++it) {
        int e = it * 2048 + tid * 4;       // element index in the tile slab
        int s = e >> 6;                    // LDS row (p*16 + rr)
        sIt[it]  = s;
        cIt[it]  = e & 63;
        gRow[it] = (s >> 4) * 128 + (s & 15);   // global row sans nt*16
    }
    float4 ld[4];

#define ISSUE(t)                                                              \
    do {                                                                      \
        _Pragma("unroll")                                                     \
        for (int it = 0; it < 4; ++it)                                        \
            ld[it] = *(const float4*)(xg + (size_t)(gRow[it] + (t) * 16) * IND + cIt[it]); \
    } while (0)

#define XWRITE(dst)                                                           \
    do {                                                                      \
        _Pragma("unroll")                                                     \
        for (int it = 0; it < 4; ++it) {                                      \
            ushort4 w4;                                                       \
            w4.x = f2bf(ld[it].x); w4.y = f2bf(ld[it].y);                     \
            w4.z = f2bf(ld[it].z); w4.w = f2bf(ld[it].w);                     \
            *(ushort4*)(&(dst)[sIt[it] * XBS + cIt[it]]) = w4;                \
        }                                                                     \
    } while (0)

    // ---- weight fragments, converted in-register (overlap tile-0 staging) --
    bf16x8 w1f[2];
#pragma unroll
    for (int ks = 0; ks < 2; ++ks)
        w1f[ks] = fragW(Wl1, ot * 16 + r, ks * 32 + q * 8);

    bf16x8 w2f[4];
#pragma unroll
    for (int ks = 0; ks < 4; ++ks)
        w2f[ks] = fragW(Wl2, ot * 16 + r, ks * 32 + q * 8);

    const float4 b1s = *(const float4*)(bl1 + ot * 16 + q * 4);
    const float4 b2s = *(const float4*)(bl2 + ot * 16 + q * 4);

    // ---- prologue: tile 0 staged, tile 1 in flight ----
    ISSUE(0);
    XWRITE(xb0);   // compiler inserts vmcnt wait for ld use (register dep)
    ISSUE(1);
    lbar();        // tile-1 loads stay in flight across

    // ======================= phase A: 8 node-tiles =========================
    for (int nt = 0; nt < 8; ++nt) {
        unsigned short* xcur = (nt & 1) ? xb1 : xb0;

        // layer 1 (K=64) for all 8 perturbations of this tile
#pragma unroll
        for (int p = 0; p < PP; ++p) {
            f32x4 a0 = (f32x4){0.f, 0.f, 0.f, 0.f};
#pragma unroll
            for (int ks = 0; ks < 2; ++ks) {
                bf16x8 xf = *(const bf16x8*)(&xcur[(p * 16 + r) * XBS + ks * 32 + q * 8]);
                a0 = mfma16(w1f[ks], xf, a0);
            }
            ushort4 v0;
            v0.x = f2bf(fmaxf(a0[0] + b1s.x, 0.f));
            v0.y = f2bf(fmaxf(a0[1] + b1s.y, 0.f));
            v0.z = f2bf(fmaxf(a0[2] + b1s.z, 0.f));
            v0.w = f2bf(fmaxf(a0[3] + b1s.w, 0.f));
            *(ushort4*)(&h1[(p * 16 + r) * LSTR + ot * 16 + q * 4]) = v0;
        }
        lbar();   // h1 complete (all 128 cols); x loads remain in flight

        // layer 2 (K=128), relu-accumulate over perturbations
        f32x4 agg0 = (f32x4){0.f, 0.f, 0.f, 0.f};
#pragma unroll
        for (int p = 0; p < PP; ++p) {
            f32x4 c0 = (f32x4){0.f, 0.f, 0.f, 0.f};
#pragma unroll
            for (int ks = 0; ks < 4; ++ks) {
                bf16x8 hf = *(const bf16x8*)(&h1[(p * 16 + r) * LSTR + ks * 32 + q * 8]);
                c0 = mfma16(w2f[ks], hf, c0);
            }
            agg0[0] += fmaxf(c0[0] + b2s.x, 0.f);
            agg0[1] += fmaxf(c0[1] + b2s.y, 0.f);
            agg0[2] += fmaxf(c0[2] + b2s.z, 0.f);
            agg0[3] += fmaxf(c0[3] + b2s.w, 0.f);
        }
        // agg for node rows nt*16..+16: exclusive (r, col) region per lane
        {
            ushort4 av;
            av.x = f2bf(agg0[0]);
            av.y = f2bf(agg0[1]);
            av.z = f2bf(agg0[2]);
            av.w = f2bf(agg0[3]);
            *(ushort4*)(&aggL[(nt * 16 + r) * LSTR + ot * 16 + q * 4]) = av;
        }

        // stage next tile's x (XWRITE consumes the in-flight loads via the
        // compiler's register-dep vmcnt — they've had a full tile to land),
        // then refill regs two tiles ahead.
        if (nt < 7) {
            if (nt & 1) XWRITE(xb0); else XWRITE(xb1);
        }
        if (nt < 6) ISSUE(nt + 2);
        lbar();   // h1 reuse + next xb ready; fresh loads NOT drained
    }

    // ================= phase B: 4x (Linear+ReLU) + pool ====================
    int cur = 0;
#pragma unroll
    for (int l = 0; l < 4; ++l) {
        const float* Wlf = (l == 0) ? Wg1 : (l == 1) ? Wg2 : (l == 2) ? Wb1 : Wb2;
        const float* bl  = (l == 0) ? bg1 : (l == 1) ? bg2 : (l == 2) ? bb1 : bb2;

        bf16x8 wf[4];
#pragma unroll
        for (int ks = 0; ks < 4; ++ks)
            wf[ks] = fragW(Wlf, ot * 16 + r, ks * 32 + q * 8);

        unsigned short* Xb = cur ? bufB : aggL;
        unsigned short* Yb = cur ? aggL : bufB;

        f32x4 acc[8];
#pragma unroll
        for (int j = 0; j < 8; ++j)
            acc[j] = (f32x4){0.f, 0.f, 0.f, 0.f};

#pragma unroll
        for (int ks = 0; ks < 4; ++ks) {
#pragma unroll
            for (int j = 0; j < 8; ++j) {
                bf16x8 xf = *(const bf16x8*)(&Xb[(j * 16 + r) * LSTR + ks * 32 + q * 8]);
                acc[j] = mfma16(wf[ks], xf, acc[j]);
            }
        }

        if (l < 3) {
            float4 bs = *(const float4*)(bl + ot * 16 + q * 4);
#pragma unroll
            for (int j = 0; j < 8; ++j) {
                ushort4 v;
                v.x = f2bf(fmaxf(acc[j][0] + bs.x, 0.f));
                v.y = f2bf(fmaxf(acc[j][1] + bs.y, 0.f));
                v.z = f2bf(fmaxf(acc[j][2] + bs.z, 0.f));
                v.w = f2bf(fmaxf(acc[j][3] + bs.w, 0.f));
                *(ushort4*)(&Yb[(j * 16 + r) * LSTR + ot * 16 + q * 4]) = v;
            }
            lbar();
            cur ^= 1;
        } else {
            float4 bs = *(const float4*)(bl + ot * 16 + q * 4);
            float s0 = 0.f, s1 = 0.f, s2 = 0.f, s3 = 0.f;
#pragma unroll
            for (int j = 0; j < 8; ++j) {
                s0 += fmaxf(acc[j][0] + bs.x, 0.f);
                s1 += fmaxf(acc[j][1] + bs.y, 0.f);
                s2 += fmaxf(acc[j][2] + bs.z, 0.f);
                s3 += fmaxf(acc[j][3] + bs.w, 0.f);
            }
#pragma unroll
            for (int m = 1; m < 16; m <<= 1) {
                s0 += __shfl_xor(s0, m, 64);
                s1 += __shfl_xor(s1, m, 64);
                s2 += __shfl_xor(s2, m, 64);
                s3 += __shfl_xor(s3, m, 64);
            }
            if (r == 0) {
                pool[ot * 16 + q * 4 + 0] = s0;   // exclusive cols per wave
                pool[ot * 16 + q * 4 + 1] = s1;
                pool[ot * 16 + q * 4 + 2] = s2;
                pool[ot * 16 + q * 4 + 3] = s3;
            }
        }
    }
    lbar();

    // ===================== decoder + log_softmax ===========================
    if (tid < 64) {
        float a0 = bd1[tid], a1 = 0.f, a2 = 0.f, a3 = 0.f;
#pragma unroll
        for (int k = 0; k < 128; k += 4) {
            a0 += pool[k]     * Wd1[(k)     * 64 + tid];
            a1 += pool[k + 1] * Wd1[(k + 1) * 64 + tid];
            a2 += pool[k + 2] * Wd1[(k + 2) * 64 + tid];
            a3 += pool[k + 3] * Wd1[(k + 3) * 64 + tid];
        }
        z[tid] = fmaxf((a0 + a1) + (a2 + a3), 0.f);
    }
    lbar();
    if (tid < OUTD) {
        float b0 = bd2[tid], b1 = 0.f;
#pragma unroll
        for (int k = 0; k < 64; k += 2) {
            b0 += z[k]     * Wd2[(k)     * OUTD + tid];
            b1 += z[k + 1] * Wd2[(k + 1) * OUTD + tid];
        }
        zz[tid] = b0 + b1;
    }
    lbar();
    if (tid == 0) {
        float m = -1e30f;
#pragma unroll
        for (int j = 0; j < OUTD; ++j) m = fmaxf(m, zz[j]);
        float ssum = 0.f;
#pragma unroll
        for (int j = 0; j < OUTD; ++j) ssum += expf(zz[j] - m);
        float ls = logf(ssum);
#pragma unroll
        for (int j = 0; j < OUTD; ++j) out[g * OUTD + j] = zz[j] - m - ls;
    }
#undef ISSUE
#undef XWRITE
}

extern "C" void kernel_launch(void* const* d_in, const int* in_sizes, int n_in,
                              void* d_out, int out_size, void* d_ws, size_t ws_size,
                              hipStream_t stream) {
    const float* x   = (const float*)d_in[0];
    // d_in[1] = ptr (unused; structure is static)
    const float* Wl1 = (const float*)d_in[2];
    const float* bl1 = (const float*)d_in[3];
    const float* Wl2 = (const float*)d_in[4];
    const float* bl2 = (const float*)d_in[5];
    const float* Wg1 = (const float*)d_in[6];
    const float* bg1 = (const float*)d_in[7];
    const float* Wg2 = (const float*)d_in[8];
    const float* bg2 = (const float*)d_in[9];
    const float* Wb1 = (const float*)d_in[10];
    const float* bb1 = (const float*)d_in[11];
    const float* Wb2 = (const float*)d_in[12];
    const float* bb2 = (const float*)d_in[13];
    const float* Wd1 = (const float*)d_in[14];
    const float* bd1 = (const float*)d_in[15];
    const float* Wd2 = (const float*)d_in[16];
    const float* bd2 = (const float*)d_in[17];

    // Single launch: weights converted in-kernel; workspace unused.
    graph_fused<<<NG, 512, 0, stream>>>(x,
                                        Wl1, bl1, Wl2, bl2,
                                        Wg1, bg1, Wg2, bg2,
                                        Wb1, bb1, Wb2, bb2,
                                        Wd1, bd1, Wd2, bd2, (float*)d_out);
}